// Round 1
// baseline (220.899 us; speedup 1.0000x reference)
//
#include <hip/hip_runtime.h>
#include <hip/hip_bf16.h>

typedef unsigned short u16;
typedef __attribute__((ext_vector_type(8))) short bf16x8;
typedef __attribute__((ext_vector_type(4))) float f32x4;

#define AS1 __attribute__((address_space(1)))
#define AS3 __attribute__((address_space(3)))

// ---- constants for this problem ----
#define Bx 8
#define Tt 2048
#define Dd 1024
#define Nn 256
#define Mm (Bx*Tt)          // 16384
#define CHAINS (Bx*Nn)      // 2048
#define NCH 32
#define TC 64               // T / NCH

__device__ __forceinline__ u16 f2bf(float f) {
  union { float f; unsigned u; } v; v.f = f;
  unsigned u = v.u;
  u += 0x7fffu + ((u >> 16) & 1u);   // RNE
  return (u16)(u >> 16);
}

__device__ __forceinline__ void gload_lds16(const void* g, void* l) {
  __builtin_amdgcn_global_load_lds((AS1 void*)(g), (AS3 void*)(l), 16, 0, 0);
}

// ---------------- x fp32 -> bf16 ----------------
__global__ void cvt_x_kernel(const float* __restrict__ x, u16* __restrict__ xb) {
  int i = blockIdx.x * blockDim.x + threadIdx.x;      // 4 floats per thread
  float4 v = ((const float4*)x)[i];
  unsigned lo = (unsigned)f2bf(v.x) | ((unsigned)f2bf(v.y) << 16);
  unsigned hi = (unsigned)f2bf(v.z) | ((unsigned)f2bf(v.w) << 16);
  ((uint2*)xb)[i] = make_uint2(lo, hi);
}

// ---------------- weight pack: transpose + convert ----------------
// z=0..2: Wa/Wb/Wc (1024x256) -> Wabc_t rows [z*256, z*256+256), ld=1024
// z=3:    Wd (1024x1024) -> Wd_t ld=1024
// z=4:    Wy (256x1024)  -> Wy_t (1024x256) ld=256
__global__ void pack_w_kernel(const float* __restrict__ Wa, const float* __restrict__ Wb,
                              const float* __restrict__ Wc, const float* __restrict__ Wd,
                              const float* __restrict__ Wy,
                              u16* __restrict__ Wabc, u16* __restrict__ Wdt, u16* __restrict__ Wyt) {
  __shared__ float tile[32][33];
  int z = blockIdx.z;
  const float* src; u16* dst; int R, C, dld;
  if (z < 3)       { src = (z==0?Wa:(z==1?Wb:Wc)); dst = Wabc + (size_t)z*256*1024; R=1024; C=256;  dld=1024; }
  else if (z == 3) { src = Wd; dst = Wdt; R=1024; C=1024; dld=1024; }
  else             { src = Wy; dst = Wyt; R=256;  C=1024; dld=256;  }
  int c0 = blockIdx.x * 32, r0 = blockIdx.y * 32;
  if (c0 >= C || r0 >= R) return;
  int tx = threadIdx.x & 31, ty = threadIdx.x >> 5;   // 32x8
  #pragma unroll
  for (int i = 0; i < 32; i += 8)
    tile[ty + i][tx] = src[(size_t)(r0 + ty + i)*C + (c0 + tx)];
  __syncthreads();
  #pragma unroll
  for (int i = 0; i < 32; i += 8) {
    int c = c0 + ty + i, r = r0 + tx;
    dst[(size_t)c*dld + r] = f2bf(tile[tx][ty + i]);
  }
}

// ---------------- GEMM: C[M,Ncols] = A[M,K] * Bt[Ncols,K]^T, bf16 in, fp32 acc ----
// EPI 0: out=abc (ld 768): col<256 sigmoid(+ba), <512 +bb, else tanh(+bc)
// EPI 1: out[row*ldo+col] = acc + b0[col]
// EPI 2: out[row*ldo+col] += acc + b0[col]
template<int EPI>
__global__ __launch_bounds__(256) void gemm_bt_kernel(
    const u16* __restrict__ A, const u16* __restrict__ Bt, int K,
    float* __restrict__ out, int ldo,
    const float* __restrict__ b0, const float* __restrict__ b1, const float* __restrict__ b2) {
  __shared__ u16 ldsA[128*32];
  __shared__ u16 ldsB[128*32];
  int tid = threadIdx.x;
  int lane = tid & 63, wid = tid >> 6;
  int wr = wid >> 1, wc = wid & 1;
  int m0 = blockIdx.y * 128, n0 = blockIdx.x * 128;

  f32x4 acc[4][4] = {};

  int g0   = wid * 2;             // 2 staging groups per wave
  int srow = lane >> 2;           // row within 16-row group
  int scol = (lane & 3) * 16;     // byte offset within 64B row-slice

  const char* Abyte = (const char*)A;
  const char* Bbyte = (const char*)Bt;

  for (int k0 = 0; k0 < K; k0 += 32) {
    #pragma unroll
    for (int i = 0; i < 2; ++i) {
      int g = g0 + i;
      int r = g*16 + srow;
      gload_lds16(Abyte + ((size_t)(m0 + r)*K + k0)*2 + scol, (char*)ldsA + g*1024);
      gload_lds16(Bbyte + ((size_t)(n0 + r)*K + k0)*2 + scol, (char*)ldsB + g*1024);
    }
    __syncthreads();

    int koff8 = lane >> 4;
    int ar = wr*64 + (lane & 15);
    int br = wc*64 + (lane & 15);
    const bf16x8* pA = (const bf16x8*)ldsA;
    const bf16x8* pB = (const bf16x8*)ldsB;
    bf16x8 af[4], bfr[4];
    #pragma unroll
    for (int mi = 0; mi < 4; ++mi) af[mi]  = pA[(ar + mi*16)*4 + koff8];
    #pragma unroll
    for (int ni = 0; ni < 4; ++ni) bfr[ni] = pB[(br + ni*16)*4 + koff8];
    #pragma unroll
    for (int mi = 0; mi < 4; ++mi)
      #pragma unroll
      for (int ni = 0; ni < 4; ++ni)
        acc[mi][ni] = __builtin_amdgcn_mfma_f32_16x16x32_bf16(af[mi], bfr[ni], acc[mi][ni], 0, 0, 0);
    __syncthreads();
  }

  // epilogue: C/D layout col=lane&15, row=(lane>>4)*4+r  [m89-verified]
  int crow = m0 + wr*64 + (lane >> 4)*4;
  int ccol = n0 + wc*64 + (lane & 15);
  #pragma unroll
  for (int mi = 0; mi < 4; ++mi) {
    #pragma unroll
    for (int ni = 0; ni < 4; ++ni) {
      int col = ccol + ni*16;
      #pragma unroll
      for (int r = 0; r < 4; ++r) {
        int row = crow + mi*16 + r;
        float v = acc[mi][ni][r];
        size_t o = (size_t)row*ldo + col;
        if (EPI == 0) {
          int seg = col >> 8, cn = col & 255;
          if (seg == 0)      v = 1.f / (1.f + __expf(-(v + b0[cn])));
          else if (seg == 1) v = v + b1[cn];
          else               v = tanhf(v + b2[cn]);
          out[o] = v;
        } else if (EPI == 1) {
          out[o] = v + b0[col];
        } else {
          out[o] = out[o] + v + b0[col];
        }
      }
    }
  }
}

// ---------------- scan: s_t = a*s + (1-a)*b ; cs = c*s ----------------
// abc layout: (m, 768) with cols [0,256)=a (post-sigmoid), [256,512)=b, [512,768)=c (post-tanh)
__global__ void scanA_kernel(const float* __restrict__ abc,
                             float* __restrict__ Asum, float* __restrict__ Usum) {
  int idx = blockIdx.x * blockDim.x + threadIdx.x;    // chunk*2048 + chain
  int chain = idx & (CHAINS - 1);
  int ch = idx >> 11;
  int bb = chain >> 8, n = chain & 255;
  const float* base = abc + (size_t)(bb*Tt + ch*TC) * 768;
  float A = 1.f, U = 0.f;
  for (int t = 0; t < TC; ++t) {
    float a = base[(size_t)t*768 + n];
    float b = base[(size_t)t*768 + 256 + n];
    U = a*U + (1.f - a)*b;
    A *= a;
  }
  Asum[idx] = A; Usum[idx] = U;
}

__global__ void scanB_kernel(const float* __restrict__ Asum, const float* __restrict__ Usum,
                             float* __restrict__ Spre) {
  int chain = blockIdx.x * blockDim.x + threadIdx.x;  // 0..2047
  float s = 0.f;
  for (int ch = 0; ch < NCH; ++ch) {
    int i = (ch << 11) + chain;
    Spre[i] = s;
    s = Asum[i]*s + Usum[i];
  }
}

__global__ void scanC_kernel(const float* __restrict__ abc, const float* __restrict__ Spre,
                             u16* __restrict__ cs) {
  int idx = blockIdx.x * blockDim.x + threadIdx.x;
  int chain = idx & (CHAINS - 1);
  int ch = idx >> 11;
  int bb = chain >> 8, n = chain & 255;
  const float* base = abc + (size_t)(bb*Tt + ch*TC) * 768;
  u16* csb = cs + (size_t)(bb*Tt + ch*TC) * 256 + n;
  float s = Spre[idx];
  for (int t = 0; t < TC; ++t) {
    float a = base[(size_t)t*768 + n];
    float b = base[(size_t)t*768 + 256 + n];
    float c = base[(size_t)t*768 + 512 + n];
    s = a*s + (1.f - a)*b;
    csb[(size_t)t*256] = f2bf(c*s);
  }
}

extern "C" void kernel_launch(void* const* d_in, const int* in_sizes, int n_in,
                              void* d_out, int out_size, void* d_ws, size_t ws_size,
                              hipStream_t stream) {
  const float* x  = (const float*)d_in[0];
  const float* Wa = (const float*)d_in[1];
  const float* ba = (const float*)d_in[2];
  const float* Wb = (const float*)d_in[3];
  const float* bb = (const float*)d_in[4];
  const float* Wc = (const float*)d_in[5];
  const float* bc = (const float*)d_in[6];
  const float* Wd = (const float*)d_in[7];
  const float* bd = (const float*)d_in[8];
  const float* Wy = (const float*)d_in[9];
  const float* by = (const float*)d_in[10];
  float* out = (float*)d_out;
  char* ws = (char*)d_ws;

  // workspace layout (bytes)
  u16*  xb   = (u16*) (ws + 0);          // 16384*1024*2 = 33,554,432
  u16*  Wabc = (u16*) (ws + 33554432);   // 768*1024*2   =  1,572,864
  u16*  Wdt  = (u16*) (ws + 35127296);   // 1024*1024*2  =  2,097,152
  u16*  Wyt  = (u16*) (ws + 37224448);   // 1024*256*2   =    524,288
  float* abc = (float*)(ws + 37748736);  // 16384*768*4  = 50,331,648
  u16*  cs   = (u16*) (ws + 88080384);   // 16384*256*2  =  8,388,608
  float* Asum= (float*)(ws + 96468992);  // 2048*32*4    =    262,144
  float* Usum= (float*)(ws + 96731136);  //                  262,144
  float* Spre= (float*)(ws + 96993280);  //                  262,144
  // total ~97,255,424 bytes

  // 1) convert x to bf16
  cvt_x_kernel<<<Mm*Dd/4/256, 256, 0, stream>>>(x, xb);
  // 2) pack weights (transposed bf16)
  pack_w_kernel<<<dim3(32, 32, 5), 256, 0, stream>>>(Wa, Wb, Wc, Wd, Wy, Wabc, Wdt, Wyt);
  // 3) abc = act(x @ [Wa|Wb|Wc] + bias)
  gemm_bt_kernel<0><<<dim3(768/128, Mm/128), 256, 0, stream>>>(xb, Wabc, Dd, abc, 768, ba, bb, bc);
  // 4) out = x @ Wd + bd
  gemm_bt_kernel<1><<<dim3(Dd/128, Mm/128), 256, 0, stream>>>(xb, Wdt, Dd, out, Dd, bd, nullptr, nullptr);
  // 5) chunked scan
  scanA_kernel<<<CHAINS*NCH/256, 256, 0, stream>>>(abc, Asum, Usum);
  scanB_kernel<<<CHAINS/256, 256, 0, stream>>>(Asum, Usum, Spre);
  scanC_kernel<<<CHAINS*NCH/256, 256, 0, stream>>>(abc, Spre, cs);
  // 6) out += cs @ Wy + by
  gemm_bt_kernel<2><<<dim3(Dd/128, Mm/128), 256, 0, stream>>>(cs, Wyt, Nn, out, Dd, by, nullptr, nullptr);
}

// Round 2
// 183.517 us; speedup vs baseline: 1.2037x; 1.2037x over previous
//
#include <hip/hip_runtime.h>
#include <hip/hip_bf16.h>

typedef unsigned short u16;
typedef __attribute__((ext_vector_type(8))) short bf16x8;
typedef __attribute__((ext_vector_type(4))) float f32x4;

#define AS1 __attribute__((address_space(1)))
#define AS3 __attribute__((address_space(3)))

// ---- constants for this problem ----
#define Bx 8
#define Tt 2048
#define Dd 1024
#define Nn 256
#define Mm (Bx*Tt)          // 16384
#define CHAINS (Bx*Nn)      // 2048
#define NCH 32
#define TC 64               // T / NCH
#define NCOMB 1792          // 768 (abc) + 1024 (d)

__device__ __forceinline__ u16 f2bf(float f) {
  union { float f; unsigned u; } v; v.f = f;
  unsigned u = v.u;
  u += 0x7fffu + ((u >> 16) & 1u);   // RNE
  return (u16)(u >> 16);
}

__device__ __forceinline__ void gload_lds16(const void* g, void* l) {
  __builtin_amdgcn_global_load_lds((AS1 void*)(g), (AS3 void*)(l), 16, 0, 0);
}

// ---------------- x fp32 -> bf16 ----------------
__global__ void cvt_x_kernel(const float* __restrict__ x, u16* __restrict__ xb) {
  int i = blockIdx.x * blockDim.x + threadIdx.x;      // 4 floats per thread
  float4 v = ((const float4*)x)[i];
  unsigned lo = (unsigned)f2bf(v.x) | ((unsigned)f2bf(v.y) << 16);
  unsigned hi = (unsigned)f2bf(v.z) | ((unsigned)f2bf(v.w) << 16);
  ((uint2*)xb)[i] = make_uint2(lo, hi);
}

// ---------------- weight pack: transpose + convert ----------------
// z=0..2: Wa/Wb/Wc (1024x256) -> Wcomb rows [z*256, z*256+256)
// z=3:    Wd (1024x1024)      -> Wcomb rows [768, 1792)
// z=4:    Wy (256x1024)       -> Wyt (1024x256) ld=256
__global__ void pack_w_kernel(const float* __restrict__ Wa, const float* __restrict__ Wb,
                              const float* __restrict__ Wc, const float* __restrict__ Wd,
                              const float* __restrict__ Wy,
                              u16* __restrict__ Wcomb, u16* __restrict__ Wyt) {
  __shared__ float tile[32][33];
  int z = blockIdx.z;
  const float* src; u16* dst; int R, C, dld;
  if (z < 3)       { src = (z==0?Wa:(z==1?Wb:Wc)); dst = Wcomb + (size_t)z*256*1024; R=1024; C=256;  dld=1024; }
  else if (z == 3) { src = Wd; dst = Wcomb + (size_t)768*1024; R=1024; C=1024; dld=1024; }
  else             { src = Wy; dst = Wyt; R=256;  C=1024; dld=256;  }
  int c0 = blockIdx.x * 32, r0 = blockIdx.y * 32;
  if (c0 >= C || r0 >= R) return;
  int tx = threadIdx.x & 31, ty = threadIdx.x >> 5;   // 32x8
  #pragma unroll
  for (int i = 0; i < 32; i += 8)
    tile[ty + i][tx] = src[(size_t)(r0 + ty + i)*C + (c0 + tx)];
  __syncthreads();
  #pragma unroll
  for (int i = 0; i < 32; i += 8) {
    int c = c0 + ty + i, r = r0 + tx;
    dst[(size_t)c*dld + r] = f2bf(tile[tx][ty + i]);
  }
}

// ---------------- GEMM: C[M,*] = A[M,K] * Bt[*,K]^T, bf16 in, fp32 acc ----
// BM=BN=128, BK=64, 4 waves, 64x64 per wave, 4x4 16x16x32 frags, 2 k-halves.
// LDS XOR swizzle (T2, both-sides): LDS linear dest for global_load_lds,
// source k-slot pre-swizzled (slot ^= row&7), ds_read uses same XOR.
// EPI 0 (combined): blockIdx.x<6 -> abc(ld 768): sigmoid(+ba)/+bb/tanh(+bc);
//                   else -> outO[row*1024 + col-768] = acc + bd[col-768]
// EPI 2: outO[row*1024+col] += acc + b0[col]
template<int EPI>
__global__ __launch_bounds__(256) void gemm_bt_kernel(
    const u16* __restrict__ A, const u16* __restrict__ Bt, int K,
    float* __restrict__ outA, float* __restrict__ outO,
    const float* __restrict__ b0, const float* __restrict__ b1,
    const float* __restrict__ b2, const float* __restrict__ b3) {
  __shared__ u16 ldsA[128*64];
  __shared__ u16 ldsB[128*64];
  const int tid = threadIdx.x;
  const int lane = tid & 63, wid = tid >> 6;
  const int wr = wid >> 1, wc = wid & 1;
  const int m0 = blockIdx.y * 128, n0 = blockIdx.x * 128;

  f32x4 acc[4][4] = {};

  // staging: lane l covers (row = g*8 + (l>>3), 16B slot = (l&7)^(l>>3))
  const int srow = lane >> 3;
  const int sq   = (lane & 7) ^ srow;
  const char* Ab = (const char*)A;
  const char* Bb = (const char*)Bt;

  // ds_read swizzle params
  const int kq  = lane >> 4;        // k-quarter within 32-wide half
  const int swz = lane & 7;         // == row&7 for all fragment rows
  const int arow = wr*64 + (lane & 15);
  const int brow = wc*64 + (lane & 15);

  for (int k0 = 0; k0 < K; k0 += 64) {
    #pragma unroll
    for (int i = 0; i < 4; ++i) {
      int g = wid*4 + i;
      int r = g*8 + srow;
      gload_lds16(Ab + ((size_t)(m0 + r)*K + k0 + sq*8)*2, (char*)ldsA + g*1024);
      gload_lds16(Bb + ((size_t)(n0 + r)*K + k0 + sq*8)*2, (char*)ldsB + g*1024);
    }
    __syncthreads();
    #pragma unroll
    for (int kk = 0; kk < 2; ++kk) {
      const int q = ((kk*4 + kq) ^ swz) * 8;   // swizzled element offset in row
      bf16x8 af[4], bfr[4];
      #pragma unroll
      for (int mi = 0; mi < 4; ++mi)
        af[mi]  = *(const bf16x8*)&ldsA[(arow + mi*16)*64 + q];
      #pragma unroll
      for (int ni = 0; ni < 4; ++ni)
        bfr[ni] = *(const bf16x8*)&ldsB[(brow + ni*16)*64 + q];
      #pragma unroll
      for (int mi = 0; mi < 4; ++mi)
        #pragma unroll
        for (int ni = 0; ni < 4; ++ni)
          acc[mi][ni] = __builtin_amdgcn_mfma_f32_16x16x32_bf16(af[mi], bfr[ni], acc[mi][ni], 0, 0, 0);
    }
    __syncthreads();
  }

  // epilogue: C/D layout col=lane&15, row=(lane>>4)*4+r  [m89-verified]
  const int crow = m0 + wr*64 + (lane >> 4)*4;
  const int ccol = wc*64 + (lane & 15);
  #pragma unroll
  for (int mi = 0; mi < 4; ++mi) {
    #pragma unroll
    for (int ni = 0; ni < 4; ++ni) {
      int coln = n0 + ccol + ni*16;
      #pragma unroll
      for (int r = 0; r < 4; ++r) {
        int row = crow + mi*16 + r;
        float v = acc[mi][ni][r];
        if (EPI == 0) {
          if (n0 < 768) {
            int seg = coln >> 8, cn = coln & 255;
            if (seg == 0)      v = 1.f / (1.f + __expf(-(v + b0[cn])));
            else if (seg == 1) v = v + b1[cn];
            else               v = tanhf(v + b2[cn]);
            outA[(size_t)row*768 + coln] = v;
          } else {
            int col = coln - 768;
            outO[(size_t)row*1024 + col] = v + b3[col];
          }
        } else {
          outO[(size_t)row*1024 + coln] += v + b0[coln];
        }
      }
    }
  }
}

// ---------------- scan: s_t = a*s + (1-a)*b ; cs = c*s ----------------
// abc layout: (m, 768) cols [0,256)=a (post-sigmoid), [256,512)=b, [512,768)=c (post-tanh)
__global__ void scanA_kernel(const float* __restrict__ abc,
                             float* __restrict__ Asum, float* __restrict__ Usum) {
  int idx = blockIdx.x * blockDim.x + threadIdx.x;    // chunk*2048 + chain
  int chain = idx & (CHAINS - 1);
  int ch = idx >> 11;
  int bb = chain >> 8, n = chain & 255;
  const float* base = abc + (size_t)(bb*Tt + ch*TC) * 768;
  float A = 1.f, U = 0.f;
  for (int t = 0; t < TC; ++t) {
    float a = base[(size_t)t*768 + n];
    float b = base[(size_t)t*768 + 256 + n];
    U = a*U + (1.f - a)*b;
    A *= a;
  }
  Asum[idx] = A; Usum[idx] = U;
}

__global__ void scanB_kernel(const float* __restrict__ Asum, const float* __restrict__ Usum,
                             float* __restrict__ Spre) {
  int chain = blockIdx.x * blockDim.x + threadIdx.x;  // 0..2047
  float s = 0.f;
  for (int ch = 0; ch < NCH; ++ch) {
    int i = (ch << 11) + chain;
    Spre[i] = s;
    s = Asum[i]*s + Usum[i];
  }
}

__global__ void scanC_kernel(const float* __restrict__ abc, const float* __restrict__ Spre,
                             u16* __restrict__ cs) {
  int idx = blockIdx.x * blockDim.x + threadIdx.x;
  int chain = idx & (CHAINS - 1);
  int ch = idx >> 11;
  int bb = chain >> 8, n = chain & 255;
  const float* base = abc + (size_t)(bb*Tt + ch*TC) * 768;
  u16* csb = cs + (size_t)(bb*Tt + ch*TC) * 256 + n;
  float s = Spre[idx];
  for (int t = 0; t < TC; ++t) {
    float a = base[(size_t)t*768 + n];
    float b = base[(size_t)t*768 + 256 + n];
    float c = base[(size_t)t*768 + 512 + n];
    s = a*s + (1.f - a)*b;
    csb[(size_t)t*256] = f2bf(c*s);
  }
}

extern "C" void kernel_launch(void* const* d_in, const int* in_sizes, int n_in,
                              void* d_out, int out_size, void* d_ws, size_t ws_size,
                              hipStream_t stream) {
  const float* x  = (const float*)d_in[0];
  const float* Wa = (const float*)d_in[1];
  const float* ba = (const float*)d_in[2];
  const float* Wb = (const float*)d_in[3];
  const float* bb = (const float*)d_in[4];
  const float* Wc = (const float*)d_in[5];
  const float* bc = (const float*)d_in[6];
  const float* Wd = (const float*)d_in[7];
  const float* bd = (const float*)d_in[8];
  const float* Wy = (const float*)d_in[9];
  const float* by = (const float*)d_in[10];
  float* out = (float*)d_out;
  char* ws = (char*)d_ws;

  // workspace layout (bytes)
  u16*  xb    = (u16*) (ws + 0);          // 16384*1024*2 = 33,554,432
  u16*  Wcomb = (u16*) (ws + 33554432);   // 1792*1024*2  =  3,670,016
  u16*  Wyt   = (u16*) (ws + 37224448);   // 1024*256*2   =    524,288
  float* abc  = (float*)(ws + 37748736);  // 16384*768*4  = 50,331,648
  u16*  cs    = (u16*) (ws + 88080384);   // 16384*256*2  =  8,388,608
  float* Asum = (float*)(ws + 96468992);  // 2048*32*4    =    262,144
  float* Usum = (float*)(ws + 96731136);  //                  262,144
  float* Spre = (float*)(ws + 96993280);  //                  262,144

  // 1) convert x to bf16
  cvt_x_kernel<<<Mm*Dd/4/256, 256, 0, stream>>>(x, xb);
  // 2) pack weights (transposed bf16, [Wa|Wb|Wc|Wd] fused)
  pack_w_kernel<<<dim3(32, 32, 5), 256, 0, stream>>>(Wa, Wb, Wc, Wd, Wy, Wcomb, Wyt);
  // 3) fused GEMM: abc = act(x@[Wa|Wb|Wc]+bias), out = x@Wd + bd
  gemm_bt_kernel<0><<<dim3(NCOMB/128, Mm/128), 256, 0, stream>>>(
      xb, Wcomb, Dd, abc, out, ba, bb, bc, bd);
  // 4) chunked scan
  scanA_kernel<<<CHAINS*NCH/256, 256, 0, stream>>>(abc, Asum, Usum);
  scanB_kernel<<<CHAINS/256, 256, 0, stream>>>(Asum, Usum, Spre);
  scanC_kernel<<<CHAINS*NCH/256, 256, 0, stream>>>(abc, Spre, cs);
  // 5) out += cs @ Wy + by
  gemm_bt_kernel<2><<<dim3(Dd/128, Mm/128), 256, 0, stream>>>(
      cs, Wyt, Nn, nullptr, out, by, nullptr, nullptr, nullptr);
}